// Round 7
// baseline (487.483 us; speedup 1.0000x reference)
//
#include <hip/hip_runtime.h>
#include <hip/hip_bf16.h>
#include <stdint.h>

// ---------------------------------------------------------------------------
// QuantizedLinear: y = x @ (qweight * scale)^T + bias
//   x [8192,4096] f32, qweight [4096,4096] i32 (exact in bf16), out f32.
// R7: R6 (16x16x32 MFMA, 0-conflict swizzle, 256x256 tile, BK=64, 8 waves,
// vmcnt(6) ledger, 1 barrier/phase, setprio, T1) + one-phase-ahead LDS read
// pipeline: ph0 reads {A-h0, B-h0, B-h1}, ph1 reads {A-h1}, ph2/ph3 read
// nothing -> ds_read latency off the critical path in 3 of 4 phases.
//
// Residency/race ledger (unchanged from R6, re-verified for hoisted reads):
//   slot lifetimes within iteration k (d = k&1, e = d^1):
//     A[d][0]: stable until ph1(k) stage   — read at ph0 only
//     A[d][1]: stable until ph0(k+1) stage — read at ph1 (hoisted)
//     B[d][0]: stable until ph2(k) stage   — read at ph0 only
//     B[d][1]: stable until ph3(k) stage   — read at ph0 (hoisted)
//   every hoisted read is register-drained before its consuming MFMA, which
//   precedes the barrier after which the overwriting stage is issued.
//   vmcnt(6) at ph3 retires through ph0(k)'s stage = all of K-tile k+1.
// ---------------------------------------------------------------------------

#define M_ 8192
#define N_ 4096
#define K_ 4096
#define NT   (K_ / 64)     // 64 K-tiles
#define NTm1 (NT - 1)
#define N8X  (M_ * K_ / 8)
#define N8W  (N_ * K_ / 8)

typedef __bf16 bf16x8 __attribute__((ext_vector_type(8)));
typedef float  f32x4  __attribute__((ext_vector_type(4)));

typedef __attribute__((address_space(1))) void gvoid_t;
typedef __attribute__((address_space(3))) void lvoid_t;

__device__ __forceinline__ void gload_lds16(const __bf16* g, __bf16* l) {
    __builtin_amdgcn_global_load_lds(
        (gvoid_t*)(uintptr_t)g,
        (lvoid_t*)(uint32_t)(uintptr_t)l, 16, 0, 0);
}

#define BAR()      asm volatile("s_barrier" ::: "memory")
#define VMCNT(n)   asm volatile("s_waitcnt vmcnt(" #n ")" ::: "memory")

// --------------------------- fused conversion ------------------------------

__global__ __launch_bounds__(256) void k_cvt(const float* __restrict__ x,
                                             const int* __restrict__ q,
                                             __bf16* __restrict__ xb,
                                             __bf16* __restrict__ wb) {
    const int stride = gridDim.x * 256;
    const int total = N8X + N8W;
    for (int i = blockIdx.x * 256 + threadIdx.x; i < total; i += stride) {
        if (i < N8X) {
            float4 a = ((const float4*)x)[(size_t)i * 2];
            float4 b = ((const float4*)x)[(size_t)i * 2 + 1];
            bf16x8 r;
            r[0] = (__bf16)a.x; r[1] = (__bf16)a.y; r[2] = (__bf16)a.z; r[3] = (__bf16)a.w;
            r[4] = (__bf16)b.x; r[5] = (__bf16)b.y; r[6] = (__bf16)b.z; r[7] = (__bf16)b.w;
            ((bf16x8*)xb)[i] = r;
        } else {
            const int j = i - N8X;
            int4 a = ((const int4*)q)[(size_t)j * 2];
            int4 b = ((const int4*)q)[(size_t)j * 2 + 1];
            bf16x8 r;
            r[0] = (__bf16)(float)a.x; r[1] = (__bf16)(float)a.y;
            r[2] = (__bf16)(float)a.z; r[3] = (__bf16)(float)a.w;
            r[4] = (__bf16)(float)b.x; r[5] = (__bf16)(float)b.y;
            r[6] = (__bf16)(float)b.z; r[7] = (__bf16)(float)b.w;
            ((bf16x8*)wb)[j] = r;
        }
    }
}

// ------------------------------- GEMM kernel -------------------------------
// LDS (bf16 elems): A slot (d,h) at (d*2+h)*8192; B at 32768 + same.
// Half-tile = 128 rows x 64 k. Storage: 16B-chunk c of row r at slot
// c ^ (r&7) (R3 swizzle, measured 0 conflicts with the 16x16 read pattern).
// Stage ledger: ph0: A[e][1]<-k+1 ; ph1: A[d][0]<-k+2 ; ph2: B[d][0]<-k+2 ;
// ph3: B[d][1]<-k+2 then MFMA then vmcnt(6) then BAR.
// MFMA 16x16x32: A/B frag row = lane&15, k-chunk = kk*4 + (lane>>4).
// C/D: col = lane&15, row = (lane>>4)*4 + j  [m89-verified]

__global__ __launch_bounds__(512, 2)
void k_gemm(const __bf16* __restrict__ A, const __bf16* __restrict__ B,
            const float* __restrict__ scale, const float* __restrict__ bias,
            float* __restrict__ C) {
    __shared__ __bf16 sm[65536];   // 128 KiB

    const int tid  = threadIdx.x;
    const int lane = tid & 63;
    const int wave = tid >> 6;
    const int wr   = wave >> 2;       // 0..1
    const int wc   = wave & 3;        // 0..3
    const int lr   = lane & 15;
    const int lg   = lane >> 4;       // 0..3

    // T1: XCD-chunked bijective swizzle (512 wgs, 512%8==0)
    const int wg   = blockIdx.x;
    const int swz  = (wg & 7) * 64 + (wg >> 3);
    const int row0 = (swz >> 4) * 256;
    const int col0 = (swz & 15) * 256;

    __bf16* smA = sm;
    __bf16* smB = sm + 32768;

    f32x4 acc[8][4];
#pragma unroll
    for (int m = 0; m < 8; ++m)
#pragma unroll
        for (int n = 0; n < 4; ++n) acc[m][n] = (f32x4){0.f, 0.f, 0.f, 0.f};

    // staging: chunk q (0..1023) -> LDS elem q*8 (linear dest).
    // logical (row=q>>3, slot=q&7); global 16B chunk = slot ^ (row&7).
    const int q0 = tid, q1 = tid + 512;
    const int r0 = q0 >> 3, s0 = q0 & 7;
    const int r1 = q1 >> 3, s1 = q1 & 7;
    const int c0 = (s0 ^ (r0 & 7)) * 8;
    const int c1 = (s1 ^ (r1 & 7)) * 8;
    const __bf16* a00 = A + (size_t)(row0 +       r0) * K_ + c0;
    const __bf16* a01 = A + (size_t)(row0 +       r1) * K_ + c1;
    const __bf16* a10 = A + (size_t)(row0 + 128 + r0) * K_ + c0;
    const __bf16* a11 = A + (size_t)(row0 + 128 + r1) * K_ + c1;
    const __bf16* b00 = B + (size_t)(col0 +       r0) * K_ + c0;
    const __bf16* b01 = B + (size_t)(col0 +       r1) * K_ + c1;
    const __bf16* b10 = B + (size_t)(col0 + 128 + r0) * K_ + c0;
    const __bf16* b11 = B + (size_t)(col0 + 128 + r1) * K_ + c1;
    const int la0 = q0 * 8, la1 = q1 * 8;

    auto stageA = [&](int d, int h, int kt) {
        __bf16* dst = smA + (d * 2 + h) * 8192;
        gload_lds16((h ? a10 : a00) + kt * 64, dst + la0);
        gload_lds16((h ? a11 : a01) + kt * 64, dst + la1);
    };
    auto stageB = [&](int d, int h, int kt) {
        __bf16* dst = smB + (d * 2 + h) * 8192;
        gload_lds16((h ? b10 : b00) + kt * 64, dst + la0);
        gload_lds16((h ? b11 : b01) + kt * 64, dst + la1);
    };
    // frag reads: chunk = kk*4 + lg, stored at slot chunk ^ (row&7)
    auto rdA = [&](int d, int mh, int m16, int kk) -> bf16x8 {
        const int mrow = wr * 64 + m16 * 16 + lr;
        const int off = (d * 2 + mh) * 8192 + mrow * 64
                      + (((kk * 4 + lg) ^ (mrow & 7)) * 8);
        return *(const bf16x8*)(smA + off);
    };
    auto rdB = [&](int d, int nh, int n16, int kk) -> bf16x8 {
        const int nrow = wc * 32 + n16 * 16 + lr;
        const int off = (d * 2 + nh) * 8192 + nrow * 64
                      + (((kk * 4 + lg) ^ (nrow & 7)) * 8);
        return *(const bf16x8*)(smB + off);
    };
    auto MF = [&](bf16x8 a, bf16x8 b, f32x4 c) -> f32x4 {
        return __builtin_amdgcn_mfma_f32_16x16x32_bf16(a, b, c, 0, 0, 0);
    };

    // prologue: K-tile 0 complete, then A0,B0,B1 of K-tile 1; vmcnt(6)
    // retires the first 4 stages (= all of K-tile 0).
    stageA(0, 0, 0); stageB(0, 0, 0); stageB(0, 1, 0); stageA(0, 1, 0);
    stageA(1, 0, 1); stageB(1, 0, 1); stageB(1, 1, 1);
    VMCNT(6);
    BAR();

    bf16x8 af0[4][2];  // A half-0 frags [m16][kk]
    bf16x8 af1[4][2];  // A half-1 frags
    bf16x8 bf0[2][2];  // B half-0 [n16][kk]
    bf16x8 bf1[2][2];  // B half-1

#pragma unroll 2
    for (int k = 0; k < NT; ++k) {
        const int d   = k & 1;
        const int e   = d ^ 1;
        const int kt1 = (k + 1 <= NTm1) ? k + 1 : NTm1;   // clamp -> dead slot
        const int kt2 = (k + 2 <= NTm1) ? k + 2 : NTm1;   // clamp -> dead slot

        // ---- phase 0: quadrant (0,0). Reads A-h0(8) + B-h0(4) for NOW,
        //      plus B-h1(4) one phase ahead.
#pragma unroll
        for (int m = 0; m < 4; ++m)
#pragma unroll
            for (int kk = 0; kk < 2; ++kk) af0[m][kk] = rdA(d, 0, m, kk);
#pragma unroll
        for (int n = 0; n < 2; ++n)
#pragma unroll
            for (int kk = 0; kk < 2; ++kk) bf0[n][kk] = rdB(d, 0, n, kk);
#pragma unroll
        for (int n = 0; n < 2; ++n)
#pragma unroll
            for (int kk = 0; kk < 2; ++kk) bf1[n][kk] = rdB(d, 1, n, kk);
        stageA(e, 1, kt1);
        __builtin_amdgcn_s_setprio(1);
#pragma unroll
        for (int kk = 0; kk < 2; ++kk)
#pragma unroll
            for (int m = 0; m < 4; ++m)
#pragma unroll
                for (int n = 0; n < 2; ++n)
                    acc[m][n] = MF(af0[m][kk], bf0[n][kk], acc[m][n]);
        __builtin_amdgcn_s_setprio(0);
        BAR();

        // ---- phase 1: quadrant (0,1) — regs resident; read A-h1(8) ahead.
#pragma unroll
        for (int m = 0; m < 4; ++m)
#pragma unroll
            for (int kk = 0; kk < 2; ++kk) af1[m][kk] = rdA(d, 1, m, kk);
        stageA(d, 0, kt2);
        __builtin_amdgcn_s_setprio(1);
#pragma unroll
        for (int kk = 0; kk < 2; ++kk)
#pragma unroll
            for (int m = 0; m < 4; ++m)
#pragma unroll
                for (int n = 0; n < 2; ++n)
                    acc[m][2 + n] = MF(af0[m][kk], bf1[n][kk], acc[m][2 + n]);
        __builtin_amdgcn_s_setprio(0);
        BAR();

        // ---- phase 2: quadrant (1,0) — no LDS reads.
        stageB(d, 0, kt2);
        __builtin_amdgcn_s_setprio(1);
#pragma unroll
        for (int kk = 0; kk < 2; ++kk)
#pragma unroll
            for (int m = 0; m < 4; ++m)
#pragma unroll
                for (int n = 0; n < 2; ++n)
                    acc[4 + m][n] = MF(af1[m][kk], bf0[n][kk], acc[4 + m][n]);
        __builtin_amdgcn_s_setprio(0);
        BAR();

        // ---- phase 3: quadrant (1,1) — no LDS reads.
        stageB(d, 1, kt2);
        __builtin_amdgcn_s_setprio(1);
#pragma unroll
        for (int kk = 0; kk < 2; ++kk)
#pragma unroll
            for (int m = 0; m < 4; ++m)
#pragma unroll
                for (int n = 0; n < 2; ++n)
                    acc[4 + m][2 + n] = MF(af1[m][kk], bf1[n][kk], acc[4 + m][2 + n]);
        __builtin_amdgcn_s_setprio(0);
        VMCNT(6);                      // K-tile k+1 fully resident (after MFMA
        BAR();                         // so the vmem wait overlaps compute)
    }

    VMCNT(0);

    // epilogue: frag C/D layout col=lane&15, row=lg*4+j (m89-verified)
    const float s = scale[0];
#pragma unroll
    for (int nh = 0; nh < 2; ++nh)
#pragma unroll
        for (int n16 = 0; n16 < 2; ++n16) {
            const int gc = col0 + nh * 128 + wc * 32 + n16 * 16 + lr;
            const float bv = bias[gc];
#pragma unroll
            for (int mh = 0; mh < 2; ++mh)
#pragma unroll
                for (int m16 = 0; m16 < 4; ++m16) {
                    const int gr = row0 + mh * 128 + wr * 64 + m16 * 16 + lg * 4;
                    const f32x4 v = acc[mh * 4 + m16][nh * 2 + n16];
#pragma unroll
                    for (int j = 0; j < 4; ++j)
                        C[(size_t)(gr + j) * N_ + gc] = v[j] * s + bv;
                }
        }
}

// ------------------------------- launcher ----------------------------------

extern "C" void kernel_launch(void* const* d_in, const int* in_sizes, int n_in,
                              void* d_out, int out_size, void* d_ws, size_t ws_size,
                              hipStream_t stream) {
    const float* x     = (const float*)d_in[0];
    const int*   qw    = (const int*)d_in[1];
    const float* scale = (const float*)d_in[2];
    const float* bias  = (const float*)d_in[3];
    float*       out   = (float*)d_out;

    __bf16* xb = (__bf16*)d_ws;
    __bf16* wb = (__bf16*)((char*)d_ws + (size_t)M_ * K_ * sizeof(__bf16));

    k_cvt<<<2048, 256, 0, stream>>>(x, qw, xb, wb);
    k_gemm<<<512, 512, 0, stream>>>(xb, wb, scale, bias, out);
}

// Round 8
// 387.101 us; speedup vs baseline: 1.2593x; 1.2593x over previous
//
#include <hip/hip_runtime.h>
#include <hip/hip_bf16.h>
#include <stdint.h>

// ---------------------------------------------------------------------------
// QuantizedLinear: y = x @ (qweight * scale)^T + bias
//   x [8192,4096] f32, qweight [4096,4096] i32 in [0,127), out f32.
// R8: INT8 MFMA GEMM. qweight is EXACT in i8; x quantized per-row symmetric
// (q = rn(x*127/rowmax), y = scale*sx_row*acc_i32 + bias). mfma_i32_16x16x64
// doubles K per instruction vs bf16 -> K-tile = 128 at the SAME per-tile
// instruction budget as R6's verified schedule (64 MFMA, 24 ds_read_b128,
// 8 gload_lds, 4 barriers, vmcnt(6) ledger, setprio, T1). NT 64 -> 32.
// Fragment read pattern (chunk = kk*4+lg, 4 distinct chunk consts/wave) is
// identical to the R3/R6 measured-zero-conflict pattern.
// ---------------------------------------------------------------------------

#define M_ 8192
#define N_ 4096
#define K_ 4096
#define NT   (K_ / 128)    // 32 K-tiles of K=128
#define NTm1 (NT - 1)

typedef int   i32x4 __attribute__((ext_vector_type(4)));

typedef __attribute__((address_space(1))) void gvoid_t;
typedef __attribute__((address_space(3))) void lvoid_t;

__device__ __forceinline__ void gload_lds16(const void* g, void* l) {
    __builtin_amdgcn_global_load_lds(
        (gvoid_t*)(uintptr_t)g,
        (lvoid_t*)(uint32_t)(uintptr_t)l, 16, 0, 0);
}

#define BAR()      asm volatile("s_barrier" ::: "memory")
#define VMCNT(n)   asm volatile("s_waitcnt vmcnt(" #n ")" ::: "memory")

// --------------------------- quantization kernel ---------------------------
// blocks [0, 8192): one block per x-row: absmax-reduce then quantize to i8.
// blocks [8192, ...): grid-stride i32 -> i8 pack of qweight (exact).

__global__ __launch_bounds__(256) void k_quant(const float* __restrict__ x,
                                               const int* __restrict__ qw,
                                               char* __restrict__ xq,
                                               char* __restrict__ wq,
                                               float* __restrict__ sxs) {
    const int b = blockIdx.x;
    if (b < M_) {
        const float* xr = x + (size_t)b * K_;
        const int t = threadIdx.x;
        float4 v[4];
        float am = 0.f;
#pragma unroll
        for (int i = 0; i < 4; ++i) {
            v[i] = ((const float4*)xr)[t * 4 + i];
            am = fmaxf(am, fmaxf(fmaxf(fabsf(v[i].x), fabsf(v[i].y)),
                                 fmaxf(fabsf(v[i].z), fabsf(v[i].w))));
        }
#pragma unroll
        for (int off = 32; off; off >>= 1)
            am = fmaxf(am, __shfl_xor(am, off));
        __shared__ float red[4];
        if ((t & 63) == 0) red[t >> 6] = am;
        __syncthreads();
        am = fmaxf(fmaxf(red[0], red[1]), fmaxf(red[2], red[3]));
        const float inv = (am > 0.f) ? 127.f / am : 0.f;
        if (t == 0) sxs[b] = (am > 0.f) ? am / 127.f : 0.f;
        union { char c[16]; int4 p; } u;
#pragma unroll
        for (int i = 0; i < 4; ++i) {
            u.c[i * 4 + 0] = (char)__float2int_rn(v[i].x * inv);
            u.c[i * 4 + 1] = (char)__float2int_rn(v[i].y * inv);
            u.c[i * 4 + 2] = (char)__float2int_rn(v[i].z * inv);
            u.c[i * 4 + 3] = (char)__float2int_rn(v[i].w * inv);
        }
        ((int4*)xq)[(size_t)b * (K_ / 16) + t] = u.p;
    } else {
        const int nb = gridDim.x - M_;
        const int total = N_ * K_ / 16;          // 16 ints -> 16 i8 per iter
        const int4* qv = (const int4*)qw;
        for (int i = (b - M_) * 256 + threadIdx.x; i < total; i += nb * 256) {
            int4 a0 = qv[(size_t)i * 4 + 0];
            int4 a1 = qv[(size_t)i * 4 + 1];
            int4 a2 = qv[(size_t)i * 4 + 2];
            int4 a3 = qv[(size_t)i * 4 + 3];
            union { char c[16]; int4 p; } u;
            u.c[0]  = (char)a0.x; u.c[1]  = (char)a0.y; u.c[2]  = (char)a0.z; u.c[3]  = (char)a0.w;
            u.c[4]  = (char)a1.x; u.c[5]  = (char)a1.y; u.c[6]  = (char)a1.z; u.c[7]  = (char)a1.w;
            u.c[8]  = (char)a2.x; u.c[9]  = (char)a2.y; u.c[10] = (char)a2.z; u.c[11] = (char)a2.w;
            u.c[12] = (char)a3.x; u.c[13] = (char)a3.y; u.c[14] = (char)a3.z; u.c[15] = (char)a3.w;
            ((int4*)wq)[i] = u.p;
        }
    }
}

// ------------------------------- GEMM kernel -------------------------------
// LDS (bytes): A slot (d,h) at (d*2+h)*16384; B at 65536 + same.
// Half-tile = 128 rows x 128 k (i8) = 16 KiB. Row = 128 B = 8 x 16B chunks.
// Storage: chunk c of row r at slot c ^ (r&7) (R3/R6 swizzle).
// Stage ledger (R6-verified, one barrier per phase, post-MFMA):
//   ph0: A[e][1]<-k+1 ; ph1: A[d][0]<-k+2 ; ph2: B[d][0]<-k+2 ;
//   ph3: B[d][1]<-k+2 then MFMA then vmcnt(6) then BAR.
// MFMA i32_16x16x64: frag row = lane&15, k-chunk = kk*4 + (lane>>4)
// (16 contiguous i8 per lane = 1 ds_read_b128).
// C/D: col = lane&15, row = (lane>>4)*4 + j (dtype-independent, m121/m127).

__global__ __launch_bounds__(512, 2)
void k_gemm(const char* __restrict__ A, const char* __restrict__ B,
            const float* __restrict__ scale, const float* __restrict__ sxs,
            const float* __restrict__ bias, float* __restrict__ C) {
    __shared__ char sm[131072];   // 128 KiB

    const int tid  = threadIdx.x;
    const int lane = tid & 63;
    const int wave = tid >> 6;
    const int wr   = wave >> 2;       // 0..1
    const int wc   = wave & 3;        // 0..3
    const int lr   = lane & 15;
    const int lg   = lane >> 4;       // 0..3

    // T1: XCD-chunked bijective swizzle (512 wgs, 512%8==0)
    const int wg   = blockIdx.x;
    const int swz  = (wg & 7) * 64 + (wg >> 3);
    const int row0 = (swz >> 4) * 256;
    const int col0 = (swz & 15) * 256;

    char* smA = sm;
    char* smB = sm + 65536;

    i32x4 acc[8][4];
#pragma unroll
    for (int m = 0; m < 8; ++m)
#pragma unroll
        for (int n = 0; n < 4; ++n) acc[m][n] = (i32x4){0, 0, 0, 0};

    // staging: chunk q (0..1023) of a half-tile -> LDS byte q*16 (linear).
    // logical (row=q>>3, slot=q&7); global 16B chunk = slot ^ (row&7).
    const int q0 = tid, q1 = tid + 512;
    const int r0 = q0 >> 3, s0 = q0 & 7;
    const int r1 = q1 >> 3, s1 = q1 & 7;
    const int c0 = (s0 ^ (r0 & 7)) * 16;
    const int c1 = (s1 ^ (r1 & 7)) * 16;
    const char* a00 = A + (size_t)(row0 +       r0) * K_ + c0;
    const char* a01 = A + (size_t)(row0 +       r1) * K_ + c1;
    const char* a10 = A + (size_t)(row0 + 128 + r0) * K_ + c0;
    const char* a11 = A + (size_t)(row0 + 128 + r1) * K_ + c1;
    const char* b00 = B + (size_t)(col0 +       r0) * K_ + c0;
    const char* b01 = B + (size_t)(col0 +       r1) * K_ + c1;
    const char* b10 = B + (size_t)(col0 + 128 + r0) * K_ + c0;
    const char* b11 = B + (size_t)(col0 + 128 + r1) * K_ + c1;
    const int la0 = q0 * 16, la1 = q1 * 16;

    auto stageA = [&](int d, int h, int kt) {
        char* dst = smA + (d * 2 + h) * 16384;
        gload_lds16((h ? a10 : a00) + kt * 128, dst + la0);
        gload_lds16((h ? a11 : a01) + kt * 128, dst + la1);
    };
    auto stageB = [&](int d, int h, int kt) {
        char* dst = smB + (d * 2 + h) * 16384;
        gload_lds16((h ? b10 : b00) + kt * 128, dst + la0);
        gload_lds16((h ? b11 : b01) + kt * 128, dst + la1);
    };
    // frag reads: chunk = kk*4 + lg, stored at slot chunk ^ (row&7)
    auto rdA = [&](int d, int mh, int m16, int kk) -> i32x4 {
        const int mrow = wr * 64 + m16 * 16 + lr;
        const int off = (d * 2 + mh) * 16384 + mrow * 128
                      + (((kk * 4 + lg) ^ (mrow & 7)) * 16);
        return *(const i32x4*)(smA + off);
    };
    auto rdB = [&](int d, int nh, int n16, int kk) -> i32x4 {
        const int nrow = wc * 32 + n16 * 16 + lr;
        const int off = (d * 2 + nh) * 16384 + nrow * 128
                      + (((kk * 4 + lg) ^ (nrow & 7)) * 16);
        return *(const i32x4*)(smB + off);
    };
    auto MF = [&](i32x4 a, i32x4 b, i32x4 c) -> i32x4 {
        return __builtin_amdgcn_mfma_i32_16x16x64_i8(a, b, c, 0, 0, 0);
    };

    // prologue: K-tile 0 complete, then A0,B0,B1 of K-tile 1; vmcnt(6)
    // retires the first 4 stages (= all of K-tile 0).
    stageA(0, 0, 0); stageB(0, 0, 0); stageB(0, 1, 0); stageA(0, 1, 0);
    stageA(1, 0, 1); stageB(1, 0, 1); stageB(1, 1, 1);
    VMCNT(6);
    BAR();

    i32x4 af[4][2];   // A frags of current half [m16][kk]
    i32x4 bf0[2][2];  // B half0 [n16][kk]
    i32x4 bf1[2][2];  // B half1

#pragma unroll 2
    for (int k = 0; k < NT; ++k) {
        const int d   = k & 1;
        const int e   = d ^ 1;
        const int kt1 = (k + 1 <= NTm1) ? k + 1 : NTm1;   // clamp -> dead slot
        const int kt2 = (k + 2 <= NTm1) ? k + 2 : NTm1;   // clamp -> dead slot

        // ---- phase 0: quadrant (0,0) — reads A-h0 (8) + B-h0 (4)
#pragma unroll
        for (int m = 0; m < 4; ++m)
#pragma unroll
            for (int kk = 0; kk < 2; ++kk) af[m][kk] = rdA(d, 0, m, kk);
#pragma unroll
        for (int n = 0; n < 2; ++n)
#pragma unroll
            for (int kk = 0; kk < 2; ++kk) bf0[n][kk] = rdB(d, 0, n, kk);
        stageA(e, 1, kt1);
        __builtin_amdgcn_s_setprio(1);
#pragma unroll
        for (int kk = 0; kk < 2; ++kk)
#pragma unroll
            for (int m = 0; m < 4; ++m)
#pragma unroll
                for (int n = 0; n < 2; ++n)
                    acc[m][n] = MF(af[m][kk], bf0[n][kk], acc[m][n]);
        __builtin_amdgcn_s_setprio(0);
        BAR();

        // ---- phase 1: quadrant (0,1) — reads B-h1 (4); A frags held
#pragma unroll
        for (int n = 0; n < 2; ++n)
#pragma unroll
            for (int kk = 0; kk < 2; ++kk) bf1[n][kk] = rdB(d, 1, n, kk);
        stageA(d, 0, kt2);
        __builtin_amdgcn_s_setprio(1);
#pragma unroll
        for (int kk = 0; kk < 2; ++kk)
#pragma unroll
            for (int m = 0; m < 4; ++m)
#pragma unroll
                for (int n = 0; n < 2; ++n)
                    acc[m][2 + n] = MF(af[m][kk], bf1[n][kk], acc[m][2 + n]);
        __builtin_amdgcn_s_setprio(0);
        BAR();

        // ---- phase 2: quadrant (1,0) — reads A-h1 (8); B0 frags held
#pragma unroll
        for (int m = 0; m < 4; ++m)
#pragma unroll
            for (int kk = 0; kk < 2; ++kk) af[m][kk] = rdA(d, 1, m, kk);
        stageB(d, 0, kt2);
        __builtin_amdgcn_s_setprio(1);
#pragma unroll
        for (int kk = 0; kk < 2; ++kk)
#pragma unroll
            for (int m = 0; m < 4; ++m)
#pragma unroll
                for (int n = 0; n < 2; ++n)
                    acc[4 + m][n] = MF(af[m][kk], bf0[n][kk], acc[4 + m][n]);
        __builtin_amdgcn_s_setprio(0);
        BAR();

        // ---- phase 3: quadrant (1,1) — no LDS reads; A1,B1 frags held
        stageB(d, 1, kt2);
        __builtin_amdgcn_s_setprio(1);
#pragma unroll
        for (int kk = 0; kk < 2; ++kk)
#pragma unroll
            for (int m = 0; m < 4; ++m)
#pragma unroll
                for (int n = 0; n < 2; ++n)
                    acc[4 + m][2 + n] = MF(af[m][kk], bf1[n][kk], acc[4 + m][2 + n]);
        __builtin_amdgcn_s_setprio(0);
        VMCNT(6);                      // K-tile k+1 fully resident (after MFMA
        BAR();                         // so the vmem wait overlaps compute)
    }

    VMCNT(0);

    // epilogue: y = (scale*sx_row)*acc + bias.
    // C/D layout col=lane&15, row=lg*4+j (m89/m121-verified, dtype-indep)
    const float s = scale[0];
#pragma unroll
    for (int nh = 0; nh < 2; ++nh)
#pragma unroll
        for (int n16 = 0; n16 < 2; ++n16) {
            const int gc = col0 + nh * 128 + wc * 32 + n16 * 16 + lr;
            const float bv = bias[gc];
#pragma unroll
            for (int mh = 0; mh < 2; ++mh)
#pragma unroll
                for (int m16 = 0; m16 < 4; ++m16) {
                    const int gr = row0 + mh * 128 + wr * 64 + m16 * 16 + lg * 4;
                    const float4 sxv = *(const float4*)&sxs[gr];  // gr % 4 == 0
                    const i32x4 v = acc[mh * 4 + m16][nh * 2 + n16];
                    C[(size_t)(gr + 0) * N_ + gc] = (float)v[0] * (s * sxv.x) + bv;
                    C[(size_t)(gr + 1) * N_ + gc] = (float)v[1] * (s * sxv.y) + bv;
                    C[(size_t)(gr + 2) * N_ + gc] = (float)v[2] * (s * sxv.z) + bv;
                    C[(size_t)(gr + 3) * N_ + gc] = (float)v[3] * (s * sxv.w) + bv;
                }
        }
}

// ------------------------------- launcher ----------------------------------

extern "C" void kernel_launch(void* const* d_in, const int* in_sizes, int n_in,
                              void* d_out, int out_size, void* d_ws, size_t ws_size,
                              hipStream_t stream) {
    const float* x     = (const float*)d_in[0];
    const int*   qw    = (const int*)d_in[1];
    const float* scale = (const float*)d_in[2];
    const float* bias  = (const float*)d_in[3];
    float*       out   = (float*)d_out;

    char*  xq  = (char*)d_ws;
    char*  wq  = xq + (size_t)M_ * K_;
    float* sxs = (float*)(wq + (size_t)N_ * K_);

    k_quant<<<M_ + 2048, 256, 0, stream>>>(x, qw, xq, wq, sxs);
    k_gemm<<<512, 512, 0, stream>>>(xq, wq, scale, sxs, bias, out);
}